// Round 5
// baseline (321.711 us; speedup 1.0000x reference)
//
#include <hip/hip_runtime.h>
#include <stdint.h>

typedef __attribute__((ext_vector_type(8))) short bf16x8;
typedef __attribute__((ext_vector_type(4))) float f32x4;

#define MFMA16(A, B, C) __builtin_amdgcn_mfma_f32_16x16x32_bf16(A, B, C, 0, 0, 0)

#define LGKM_GUARD() do { asm volatile("s_waitcnt lgkmcnt(0)" ::: "memory"); \
                          __builtin_amdgcn_sched_barrier(0); } while (0)

static __device__ __forceinline__ unsigned short f2bf(float f) {
  uint32_t u = __float_as_uint(f);
  u = (u + 0x7fffu + ((u >> 16) & 1u)) >> 16;
  return (unsigned short)u;
}

static __device__ __forceinline__ bf16x8 pack8(float4 a, float4 b) {
  bf16x8 r;
  r[0] = (short)f2bf(a.x); r[1] = (short)f2bf(a.y);
  r[2] = (short)f2bf(a.z); r[3] = (short)f2bf(a.w);
  r[4] = (short)f2bf(b.x); r[5] = (short)f2bf(b.y);
  r[6] = (short)f2bf(b.z); r[7] = (short)f2bf(b.w);
  return r;
}

// ======== K0: weight prep only (x is no longer permuted) =================================
// bid < 64: Wsr -> W2sr frag-major; else Wq/Wp/Wkv frag-major.
__global__ __launch_bounds__(256) void prep_kernel(
    const float* __restrict__ Wq, const float* __restrict__ Wkv,
    const float* __restrict__ Wp, const float* __restrict__ Wsr,
    unsigned short* __restrict__ Wq2, unsigned short* __restrict__ Wkv2,
    unsigned short* __restrict__ Wp2, unsigned short* __restrict__ W2sr) {
  const int bid = blockIdx.x;
  const int tid = threadIdx.x;
  if (bid < 64) {
    // Wsr [o][c][s] -> W2sr[((s*4 + c>>5)*128 + o)*32 + (c&31)]
    int t = bid * 256 + tid;                 // < 16384
    int o = t >> 7, c = t & 127;
    const float4* wp = (const float4*)(Wsr + (size_t)t * 64);
#pragma unroll
    for (int s4 = 0; s4 < 16; ++s4) {
      float4 v = wp[s4];
#pragma unroll
      for (int e = 0; e < 4; ++e) {
        int s = s4 * 4 + e;
        float f = (e == 0) ? v.x : (e == 1) ? v.y : (e == 2) ? v.z : v.w;
        W2sr[(size_t)((s * 4 + (c >> 5)) * 128 + o) * 32 + (c & 31)] = f2bf(f);
      }
    }
    return;
  }
  int t = (bid - 64) * 256 + tid;            // < 65536
  if (t < 16384) {
    int o = t >> 7, c = t & 127;
    Wq2[((c >> 5) * 128 + o) * 32 + (c & 31)] = f2bf(Wq[t]);
  } else if (t < 32768) {
    int u = t - 16384;
    int o = u >> 7, c = u & 127;
    Wp2[((c >> 5) * 128 + o) * 32 + (c & 31)] = f2bf(Wp[u]);
  } else {
    int u = t - 32768;
    int o = u >> 7, c = u & 127;
    Wkv2[((c >> 5) * 256 + o) * 32 + (c & 31)] = f2bf(Wkv[u]);
  }
}

// ======== K1: conv split-K patch-GEMM; stages x rows f32->bf16 in LDS (swizzled) =========
// grid (128 patch-tiles, 4 kh-pair splits). Block stages 2 image rows (64 KB LDS).
// Writes per-wave f32 partials to scratch[16][2048][128].
__global__ __launch_bounds__(256, 2) void conv_split_kernel(
    const float* __restrict__ x, const unsigned short* __restrict__ W2sr,
    float* __restrict__ scratch) {
  const int tid = threadIdx.x;
  const int wave = tid >> 6, l = tid & 63, lg = l >> 4, lr = l & 15;
  const int pt = blockIdx.x;                 // (b, ii): 16 patches jj = 0..15
  const int ks = blockIdx.y;                 // kh pair {2ks, 2ks+1}
  const int b = pt >> 4, ii = pt & 15;

  __shared__ __align__(16) unsigned short Xc[2][16384];   // 64 KB, jj-XOR swizzled

  // stage rows y0, y0+1 (contiguous 32768 f32), coalesced, convert to bf16
  const float* src = x + (size_t)b * 2097152 + (size_t)(ii * 8 + ks * 2) * 16384;
#pragma unroll
  for (int it = 0; it < 32; ++it) {
    int f = it * 1024 + tid * 4;             // 0..32767
    float4 v = *(const float4*)(src + f);
    int row = f >> 14, o = f & 16383;
    int byteoff = (o * 2) ^ (((o >> 10) & 7) << 4);   // jj = o>>10
    ushort4 h;
    h.x = f2bf(v.x); h.y = f2bf(v.y); h.z = f2bf(v.z); h.w = f2bf(v.w);
    *(ushort4*)((char*)&Xc[row][0] + byteoff) = h;
  }
  __syncthreads();

  const f32x4 zr = {0.f, 0.f, 0.f, 0.f};
  f32x4 acc[8];
#pragma unroll
  for (int ct = 0; ct < 8; ++ct) acc[ct] = zr;

  for (int kt = 0; kt < 16; ++kt) {
    const int k = ks * 2048 + wave * 512 + kt * 32;
    const int s = k >> 7, c0t = (k >> 5) & 3;
    const int kw = s & 7, yl = (s >> 3) & 1;
    int o_r = (lr * 8 + kw) * 128 + c0t * 32 + lg * 8;
    int byteoff = (o_r * 2) ^ ((lr & 7) << 4);        // same XOR fn of jj=lr
    bf16x8 af = *(const bf16x8*)((const char*)&Xc[yl][0] + byteoff);
    const unsigned short* wb = W2sr + (size_t)(k >> 5) * 4096;
#pragma unroll
    for (int ct = 0; ct < 8; ++ct) {
      bf16x8 bfr = *(const bf16x8*)(wb + (ct * 16 + lr) * 32 + lg * 8);
      acc[ct] = MFMA16(af, bfr, acc[ct]);
    }
  }

  // per-wave partial store (no reduce barrier): split index = ks*4 + wave
#pragma unroll
  for (int ct = 0; ct < 8; ++ct)
#pragma unroll
    for (int r = 0; r < 4; ++r)
      scratch[((size_t)((ks * 4 + wave) * 2048 + pt * 16 + lg * 4 + r)) * 128 + ct * 16 + lr] = acc[ct][r];
}

// ======== K2: sum 16 partials + bias + LayerNorm + KV proj (frag-major K2/V2) ============
__global__ __launch_bounds__(256, 2) void ln_kv_kernel(
    const float* __restrict__ scratch, const float* __restrict__ bsr,
    const float* __restrict__ gamma, const float* __restrict__ beta,
    const unsigned short* __restrict__ Wkv2, const float* __restrict__ bkv,
    unsigned short* __restrict__ K2, unsigned short* __restrict__ V2) {
  const int tid = threadIdx.x;
  const int wave = tid >> 6, l = tid & 63, lg = l >> 4, lr = l & 15;
  const int blk = blockIdx.x;

  __shared__ unsigned short lns[16][136];

  {
    const int row = tid >> 4, c0 = (tid & 15) * 8;
    const int p = blk * 16 + row;
    float vals[8];
#pragma unroll
    for (int cc = 0; cc < 8; ++cc) vals[cc] = bsr[c0 + cc];
#pragma unroll
    for (int ksp = 0; ksp < 16; ++ksp) {
      const float4* sp = (const float4*)(scratch + ((size_t)(ksp * 2048 + p)) * 128 + c0);
      float4 a = sp[0], bb = sp[1];
      vals[0] += a.x; vals[1] += a.y; vals[2] += a.z; vals[3] += a.w;
      vals[4] += bb.x; vals[5] += bb.y; vals[6] += bb.z; vals[7] += bb.w;
    }
    float s1 = 0.f, s2 = 0.f;
#pragma unroll
    for (int cc = 0; cc < 8; ++cc) { s1 += vals[cc]; s2 += vals[cc] * vals[cc]; }
#pragma unroll
    for (int msk = 1; msk < 16; msk <<= 1) { s1 += __shfl_xor(s1, msk); s2 += __shfl_xor(s2, msk); }
    float mean = s1 * (1.f / 128.f);
    float var = s2 * (1.f / 128.f) - mean * mean;
    float rstd = rsqrtf(var + 1e-5f);
#pragma unroll
    for (int cc = 0; cc < 8; ++cc) {
      int c = c0 + cc;
      lns[row][c] = f2bf((vals[cc] - mean) * rstd * gamma[c] + beta[c]);
    }
  }
  __syncthreads();

  const f32x4 zr = {0.f, 0.f, 0.f, 0.f};
  f32x4 kv[4];
#pragma unroll
  for (int q = 0; q < 4; ++q) kv[q] = zr;
#pragma unroll
  for (int kt = 0; kt < 4; ++kt) {
    bf16x8 af = *(const bf16x8*)(&lns[lr][kt * 32 + lg * 8]);
#pragma unroll
    for (int q = 0; q < 4; ++q) {
      bf16x8 bfr = *(const bf16x8*)(Wkv2 + (kt * 256 + (wave * 4 + q) * 16 + lr) * 32 + lg * 8);
      kv[q] = MFMA16(af, bfr, kv[q]);
    }
  }
#pragma unroll
  for (int q = 0; q < 4; ++q)
#pragma unroll
    for (int r = 0; r < 4; ++r) {
      int o2 = (wave * 4 + q) * 16 + lr;
      int mrow = lg * 4 + r;
      int pp = blk * 16 + mrow;
      int bb = pp >> 8, mm = pp & 255;
      float val = kv[q][r] + bkv[o2];
      unsigned short hv = f2bf(val);
      if (o2 < 128) {                       // K2: [(b*2+h)*2 + d>>5][m][d&31]
        int h = o2 >> 6, d = o2 & 63;
        K2[((size_t)((bb * 2 + h) * 2 + (d >> 5)) * 256 + mm) * 32 + (d & 31)] = hv;
      } else {                              // V2: [(b*2+h)*8 + m>>5][d][m&31]
        int o3 = o2 - 128, h = o3 >> 6, d = o3 & 63;
        V2[((size_t)((bb * 2 + h) * 8 + (mm >> 5)) * 64 + d) * 32 + (mm & 31)] = hv;
      }
    }
}

// ======== K3: fused Qproj + attention + out-proj; zero barriers, wave-private LDS ========
// grid (256 n-tiles of 64 rows, 8 batches); per wave 16 rows; 50 KB LDS -> 3 blocks/CU.
__global__ __launch_bounds__(256, 3) void attn_kernel(
    const float* __restrict__ x, const float* __restrict__ bq, const float* __restrict__ bp,
    const unsigned short* __restrict__ Wq2, const unsigned short* __restrict__ Wp2,
    const unsigned short* __restrict__ K2, const unsigned short* __restrict__ V2,
    float* __restrict__ out) {
  const int tid = threadIdx.x;
  const int wave = tid >> 6, l = tid & 63, lg = l >> 4, lr = l & 15;
  const int b = blockIdx.y;
  const int n0 = blockIdx.x * 64 + wave * 16;     // this wave's 16 rows

  __shared__ __align__(16) unsigned short XQ[4][16 * 136];  // per-wave: Xs, then Qs
  __shared__ __align__(16) unsigned short PS[4][16 * 264];  // per-wave: P, then O, then Os(f32)

  unsigned short* Xs = &XQ[wave][0];              // [16][136] bf16
  unsigned short* Ps = &PS[wave][0];              // [16][264] bf16

  const f32x4 zr = {0.f, 0.f, 0.f, 0.f};

  // ---- stage 16 x rows f32 -> bf16 into Xs (global reads lane-consecutive 16B) ----
  {
    const float* src = x + ((size_t)b * 16384 + n0) * 128;
#pragma unroll
    for (int q = 0; q < 8; ++q) {
      int f = q * 256 + l * 4;                    // 0..2047
      float4 v = *(const float4*)(src + f);
      int row = f >> 7, col = f & 127;
      ushort4 h;
      h.x = f2bf(v.x); h.y = f2bf(v.y); h.z = f2bf(v.z); h.w = f2bf(v.w);
      *(ushort4*)(Xs + row * 136 + col) = h;
    }
  }
  LGKM_GUARD();

  // ---- Q projection (scale 1/8 folded; Xs consumed to regs, then Qs overwrites slab) ----
  {
    bf16x8 af[4];
#pragma unroll
    for (int kt = 0; kt < 4; ++kt)
      af[kt] = *(const bf16x8*)(Xs + lr * 136 + kt * 32 + lg * 8);
    LGKM_GUARD();                                 // WAR: af loads done before Qs overwrite
    f32x4 qa[8];
#pragma unroll
    for (int ct = 0; ct < 8; ++ct) qa[ct] = zr;
#pragma unroll
    for (int kt = 0; kt < 4; ++kt)
#pragma unroll
      for (int ct = 0; ct < 8; ++ct) {
        bf16x8 bfr = *(const bf16x8*)(Wq2 + (kt * 128 + ct * 16 + lr) * 32 + lg * 8);
        qa[ct] = MFMA16(af[kt], bfr, qa[ct]);
      }
#pragma unroll
    for (int ct = 0; ct < 8; ++ct)
#pragma unroll
      for (int r = 0; r < 4; ++r)
        Xs[(lg * 4 + r) * 136 + ct * 16 + lr] = f2bf((qa[ct][r] + bq[ct * 16 + lr]) * 0.125f);
  }

  f32x4 oacc[2][4];
#pragma unroll
  for (int h2 = 0; h2 < 2; ++h2)
#pragma unroll
    for (int dt = 0; dt < 4; ++dt) oacc[h2][dt] = zr;

  for (int h = 0; h < 2; ++h) {
    // S^T = mfma(K, Q): lane owns n = lr, m = mt*16 + lg*4 + r
    f32x4 sacc[16];
#pragma unroll
    for (int mt = 0; mt < 16; ++mt) sacc[mt] = zr;
#pragma unroll
    for (int d0 = 0; d0 < 64; d0 += 32) {
      const unsigned short* kbase = K2 + (size_t)((b * 2 + h) * 2 + (d0 >> 5)) * 8192;
      bf16x8 qf = *(const bf16x8*)(Xs + lr * 136 + h * 64 + d0 + lg * 8);
#pragma unroll
      for (int mt = 0; mt < 16; ++mt) {
        bf16x8 kf = *(const bf16x8*)(kbase + (mt * 16 + lr) * 32 + lg * 8);
        sacc[mt] = MFMA16(kf, qf, sacc[mt]);
      }
    }
    // softmax over m = 256
    float mx = -1e30f;
#pragma unroll
    for (int mt = 0; mt < 16; ++mt)
#pragma unroll
      for (int r = 0; r < 4; ++r) mx = fmaxf(mx, sacc[mt][r]);
    mx = fmaxf(mx, __shfl_xor(mx, 16));
    mx = fmaxf(mx, __shfl_xor(mx, 32));
    float sum = 0.f;
#pragma unroll
    for (int mt = 0; mt < 16; ++mt)
#pragma unroll
      for (int r = 0; r < 4; ++r) {
        float pv = __expf(sacc[mt][r] - mx);
        sacc[mt][r] = pv; sum += pv;
      }
    sum += __shfl_xor(sum, 16);
    sum += __shfl_xor(sum, 32);
    float inv = 1.f / sum;
    if (h == 1) LGKM_GUARD();                     // WAR: prev head's pf reads done
#pragma unroll
    for (int mt = 0; mt < 16; ++mt) {
      unsigned int w0 = (unsigned int)f2bf(sacc[mt][0] * inv) | ((unsigned int)f2bf(sacc[mt][1] * inv) << 16);
      unsigned int w1 = (unsigned int)f2bf(sacc[mt][2] * inv) | ((unsigned int)f2bf(sacc[mt][3] * inv) << 16);
      uint2 pw; pw.x = w0; pw.y = w1;
      *(uint2*)(Ps + lr * 264 + mt * 16 + lg * 4) = pw;   // P[n=lr][m]
    }

    // PV: O[16 n][64 d] += P @ V_h (V-frags contiguous, L2-hot)
#pragma unroll
    for (int ki = 0; ki < 8; ++ki) {
      const unsigned short* vbase = V2 + (size_t)((b * 2 + h) * 8 + ki) * 2048;
      bf16x8 pf = *(const bf16x8*)(Ps + lr * 264 + ki * 32 + lg * 8);
#pragma unroll
      for (int dt = 0; dt < 4; ++dt) {
        bf16x8 vf = *(const bf16x8*)(vbase + (dt * 16 + lr) * 32 + lg * 8);
        oacc[h][dt] = MFMA16(pf, vf, oacc[h][dt]);
      }
    }
  }  // head

  LGKM_GUARD();  // WAR: last pf reads done before O overwrites Ps slab
  // ---- O -> LDS (bf16, [16][136] in Ps slab) ----
#pragma unroll
  for (int h = 0; h < 2; ++h)
#pragma unroll
    for (int dt = 0; dt < 4; ++dt)
#pragma unroll
      for (int r = 0; r < 4; ++r)
        Ps[(lg * 4 + r) * 136 + h * 64 + dt * 16 + lr] = f2bf(oacc[h][dt][r]);

  // ---- out-proj ----
  bf16x8 af2[4];
#pragma unroll
  for (int kt = 0; kt < 4; ++kt)
    af2[kt] = *(const bf16x8*)(Ps + lr * 136 + kt * 32 + lg * 8);
  LGKM_GUARD();                                   // WAR: af2 loaded before Os overwrite
  f32x4 yacc[8];
#pragma unroll
  for (int ct = 0; ct < 8; ++ct) yacc[ct] = zr;
#pragma unroll
  for (int kt = 0; kt < 4; ++kt)
#pragma unroll
    for (int ct = 0; ct < 8; ++ct) {
      bf16x8 bfr = *(const bf16x8*)(Wp2 + (kt * 128 + ct * 16 + lr) * 32 + lg * 8);
      yacc[ct] = MFMA16(af2[kt], bfr, yacc[ct]);
    }

  // ---- stage result f32 in Ps slab ([16][132]) and store coalesced ----
  float* Osf = (float*)Ps;
#pragma unroll
  for (int ct = 0; ct < 8; ++ct)
#pragma unroll
    for (int r = 0; r < 4; ++r)
      Osf[(lg * 4 + r) * 132 + ct * 16 + lr] = yacc[ct][r] + bp[ct * 16 + lr];

  {
    float* dst = out + ((size_t)b * 16384 + n0) * 128;
#pragma unroll
    for (int q = 0; q < 8; ++q) {
      int f = q * 256 + l * 4;
      int row = f >> 7, col = f & 127;
      float4 v = *(const float4*)(Osf + row * 132 + col);
      *(float4*)(dst + f) = v;
    }
  }
}

extern "C" void kernel_launch(void* const* d_in, const int* in_sizes, int n_in,
                              void* d_out, int out_size, void* d_ws, size_t ws_size,
                              hipStream_t stream) {
  const float* x = (const float*)d_in[0];
  const float* Wq = (const float*)d_in[3];
  const float* bq = (const float*)d_in[4];
  const float* Wkv = (const float*)d_in[5];
  const float* bkv = (const float*)d_in[6];
  const float* Wp = (const float*)d_in[7];
  const float* bp = (const float*)d_in[8];
  const float* Wsr = (const float*)d_in[9];
  const float* bsr = (const float*)d_in[10];
  const float* gamma = (const float*)d_in[11];
  const float* beta = (const float*)d_in[12];
  float* out = (float*)d_out;

  unsigned short* ws = (unsigned short*)d_ws;
  unsigned short* Wq2 = ws;                   // 16384
  unsigned short* Wp2 = ws + 16384;           // 16384
  unsigned short* Wkv2 = ws + 32768;          // 32768
  unsigned short* W2sr = ws + 65536;          // 1048576
  unsigned short* K2 = ws + 1114112;          // 262144
  unsigned short* V2 = ws + 1376256;          // 262144
  float* scratch = (float*)(ws + 1638400);    // 16*2048*128 f32 = 16 MB partials

  prep_kernel<<<320, 256, 0, stream>>>(Wq, Wkv, Wp, Wsr, Wq2, Wkv2, Wp2, W2sr);
  conv_split_kernel<<<dim3(128, 4), 256, 0, stream>>>(x, W2sr, scratch);
  ln_kv_kernel<<<128, 256, 0, stream>>>(scratch, bsr, gamma, beta, Wkv2, bkv, K2, V2);
  attn_kernel<<<dim3(256, 8), 256, 0, stream>>>(x, bq, bp, Wq2, Wp2, K2, V2, out);
}

// Round 6
// 281.791 us; speedup vs baseline: 1.1417x; 1.1417x over previous
//
#include <hip/hip_runtime.h>
#include <hip/hip_bf16.h>
#include <stdint.h>

typedef __attribute__((ext_vector_type(8))) short bf16x8;
typedef __attribute__((ext_vector_type(4))) float f32x4;

#define MFMA16(A, B, C) __builtin_amdgcn_mfma_f32_16x16x32_bf16(A, B, C, 0, 0, 0)

#define LGKM_GUARD() do { asm volatile("s_waitcnt lgkmcnt(0)" ::: "memory"); \
                          __builtin_amdgcn_sched_barrier(0); } while (0)

// 0.125 (1/sqrt(64)) * log2(e), folded into Q so softmax uses exp2
#define QSCL 0.1803368801111204f

static __device__ __forceinline__ unsigned short bfr(float f) {
  __hip_bfloat16 h = __float2bfloat16(f);     // RNE, native cvt
  return *reinterpret_cast<unsigned short*>(&h);
}

static __device__ __forceinline__ unsigned int pk2(float a, float b) {
  float2 t; t.x = a; t.y = b;
  __hip_bfloat162 h = __float22bfloat162_rn(t);  // v_cvt_pk_bf16_f32
  return *reinterpret_cast<unsigned int*>(&h);
}

// ======== K0: weight prep (frag-major bf16) =============================================
__global__ __launch_bounds__(256) void prep_kernel(
    const float* __restrict__ Wq, const float* __restrict__ Wkv,
    const float* __restrict__ Wp, const float* __restrict__ Wsr,
    unsigned short* __restrict__ Wq2, unsigned short* __restrict__ Wkv2,
    unsigned short* __restrict__ Wp2, unsigned short* __restrict__ W2sr) {
  const int bid = blockIdx.x;
  const int tid = threadIdx.x;
  if (bid < 64) {
    // Wsr [o][c][s] -> W2sr[((s*4 + c>>5)*128 + o)*32 + (c&31)]
    int t = bid * 256 + tid;                 // < 16384
    int o = t >> 7, c = t & 127;
    const float4* wp = (const float4*)(Wsr + (size_t)t * 64);
#pragma unroll
    for (int s4 = 0; s4 < 16; ++s4) {
      float4 v = wp[s4];
#pragma unroll
      for (int e = 0; e < 4; ++e) {
        int s = s4 * 4 + e;
        float f = (e == 0) ? v.x : (e == 1) ? v.y : (e == 2) ? v.z : v.w;
        W2sr[(size_t)((s * 4 + (c >> 5)) * 128 + o) * 32 + (c & 31)] = bfr(f);
      }
    }
    return;
  }
  int t = (bid - 64) * 256 + tid;            // < 65536
  if (t < 16384) {
    int o = t >> 7, c = t & 127;
    Wq2[((c >> 5) * 128 + o) * 32 + (c & 31)] = bfr(Wq[t]);
  } else if (t < 32768) {
    int u = t - 16384;
    int o = u >> 7, c = u & 127;
    Wp2[((c >> 5) * 128 + o) * 32 + (c & 31)] = bfr(Wp[u]);
  } else {
    int u = t - 32768;
    int o = u >> 7, c = u & 127;
    Wkv2[((c >> 5) * 256 + o) * 32 + (c & 31)] = bfr(Wkv[u]);
  }
}

// ======== K1: conv split-K patch-GEMM; LDS-staged rows (XOR swizzle both sides) ==========
__global__ __launch_bounds__(256, 2) void conv_split_kernel(
    const float* __restrict__ x, const unsigned short* __restrict__ W2sr,
    float* __restrict__ scratch) {
  const int tid = threadIdx.x;
  const int wave = tid >> 6, l = tid & 63, lg = l >> 4, lr = l & 15;
  const int pt = blockIdx.x;                 // (b, ii)
  const int ks = blockIdx.y;                 // kh pair {2ks, 2ks+1}
  const int b = pt >> 4, ii = pt & 15;

  __shared__ __align__(16) unsigned short Xc[2][16384];   // 64 KB

  const float* src = x + (size_t)b * 2097152 + (size_t)(ii * 8 + ks * 2) * 16384;
#pragma unroll
  for (int it = 0; it < 32; ++it) {
    int f = it * 1024 + tid * 4;             // 0..32767
    float4 v = *(const float4*)(src + f);
    int row = f >> 14, o = f & 16383;
    int byteoff = (o * 2) ^ (((o >> 10) & 7) << 4);   // jj = o>>10
    ushort4 h;
    h.x = bfr(v.x); h.y = bfr(v.y); h.z = bfr(v.z); h.w = bfr(v.w);
    *(ushort4*)((char*)&Xc[row][0] + byteoff) = h;
  }
  __syncthreads();

  const f32x4 zr = {0.f, 0.f, 0.f, 0.f};
  f32x4 acc[8];
#pragma unroll
  for (int ct = 0; ct < 8; ++ct) acc[ct] = zr;

  for (int kt = 0; kt < 16; ++kt) {
    const int k = ks * 2048 + wave * 512 + kt * 32;
    const int s = k >> 7, c0t = (k >> 5) & 3;
    const int kw = s & 7, yl = (s >> 3) & 1;
    int o_r = (lr * 8 + kw) * 128 + c0t * 32 + lg * 8;
    int byteoff = (o_r * 2) ^ ((lr & 7) << 4);
    bf16x8 af = *(const bf16x8*)((const char*)&Xc[yl][0] + byteoff);
    const unsigned short* wb = W2sr + (size_t)(k >> 5) * 4096;
#pragma unroll
    for (int ct = 0; ct < 8; ++ct) {
      bf16x8 bfrg = *(const bf16x8*)(wb + (ct * 16 + lr) * 32 + lg * 8);
      acc[ct] = MFMA16(af, bfrg, acc[ct]);
    }
  }

#pragma unroll
  for (int ct = 0; ct < 8; ++ct)
#pragma unroll
    for (int r = 0; r < 4; ++r)
      scratch[((size_t)((ks * 4 + wave) * 2048 + pt * 16 + lg * 4 + r)) * 128 + ct * 16 + lr] = acc[ct][r];
}

// ======== K2: sum 16 partials + bias + LayerNorm + KV proj ===============================
__global__ __launch_bounds__(256, 2) void ln_kv_kernel(
    const float* __restrict__ scratch, const float* __restrict__ bsr,
    const float* __restrict__ gamma, const float* __restrict__ beta,
    const unsigned short* __restrict__ Wkv2, const float* __restrict__ bkv,
    unsigned short* __restrict__ K2, unsigned short* __restrict__ V2) {
  const int tid = threadIdx.x;
  const int wave = tid >> 6, l = tid & 63, lg = l >> 4, lr = l & 15;
  const int blk = blockIdx.x;

  __shared__ unsigned short lns[16][136];

  {
    const int row = tid >> 4, c0 = (tid & 15) * 8;
    const int p = blk * 16 + row;
    float vals[8];
#pragma unroll
    for (int cc = 0; cc < 8; ++cc) vals[cc] = bsr[c0 + cc];
#pragma unroll
    for (int ksp = 0; ksp < 16; ++ksp) {
      const float4* sp = (const float4*)(scratch + ((size_t)(ksp * 2048 + p)) * 128 + c0);
      float4 a = sp[0], bb = sp[1];
      vals[0] += a.x; vals[1] += a.y; vals[2] += a.z; vals[3] += a.w;
      vals[4] += bb.x; vals[5] += bb.y; vals[6] += bb.z; vals[7] += bb.w;
    }
    float s1 = 0.f, s2 = 0.f;
#pragma unroll
    for (int cc = 0; cc < 8; ++cc) { s1 += vals[cc]; s2 += vals[cc] * vals[cc]; }
#pragma unroll
    for (int msk = 1; msk < 16; msk <<= 1) { s1 += __shfl_xor(s1, msk); s2 += __shfl_xor(s2, msk); }
    float mean = s1 * (1.f / 128.f);
    float var = s2 * (1.f / 128.f) - mean * mean;
    float rstd = rsqrtf(var + 1e-5f);
#pragma unroll
    for (int cc = 0; cc < 8; ++cc) {
      int c = c0 + cc;
      lns[row][c] = bfr((vals[cc] - mean) * rstd * gamma[c] + beta[c]);
    }
  }
  __syncthreads();

  const f32x4 zr = {0.f, 0.f, 0.f, 0.f};
  f32x4 kv[4];
#pragma unroll
  for (int q = 0; q < 4; ++q) kv[q] = zr;
#pragma unroll
  for (int kt = 0; kt < 4; ++kt) {
    bf16x8 af = *(const bf16x8*)(&lns[lr][kt * 32 + lg * 8]);
#pragma unroll
    for (int q = 0; q < 4; ++q) {
      bf16x8 bfrg = *(const bf16x8*)(Wkv2 + (kt * 256 + (wave * 4 + q) * 16 + lr) * 32 + lg * 8);
      kv[q] = MFMA16(af, bfrg, kv[q]);
    }
  }
#pragma unroll
  for (int q = 0; q < 4; ++q)
#pragma unroll
    for (int r = 0; r < 4; ++r) {
      int o2 = (wave * 4 + q) * 16 + lr;
      int pp = blk * 16 + lg * 4 + r;
      int bb = pp >> 8, mm = pp & 255;
      float val = kv[q][r] + bkv[o2];
      unsigned short hv = bfr(val);
      if (o2 < 128) {                       // K2: [(b*2+h)*2 + d>>5][m][d&31]
        int h = o2 >> 6, d = o2 & 63;
        K2[((size_t)((bb * 2 + h) * 2 + (d >> 5)) * 256 + mm) * 32 + (d & 31)] = hv;
      } else {                              // V2: [(b*2+h)*8 + m>>5][d][m&31]
        int o3 = o2 - 128, h = o3 >> 6, d = o3 & 63;
        V2[((size_t)((bb * 2 + h) * 8 + (mm >> 5)) * 64 + d) * 32 + (mm & 31)] = hv;
      }
    }
}

// ======== K3: Q projection -> frag-major Qf (pre-scaled by 0.125*log2e) ==================
// grid (256, 8): per wave 16 rows. LDS 17.4 KB/block.
__global__ __launch_bounds__(256, 4) void qproj_kernel(
    const float* __restrict__ x, const float* __restrict__ bq,
    const unsigned short* __restrict__ Wq2, unsigned short* __restrict__ Qf) {
  const int tid = threadIdx.x;
  const int wave = tid >> 6, l = tid & 63, lg = l >> 4, lr = l & 15;
  const int b = blockIdx.y;
  const int nt = blockIdx.x * 4 + wave;           // n-tile of 16 rows
  const int n0 = nt * 16;

  __shared__ __align__(16) unsigned short XQ[4][16 * 136];
  unsigned short* Xs = &XQ[wave][0];

  // stage 16 rows f32 -> bf16, coalesced
  const float* src = x + ((size_t)b * 16384 + n0) * 128;
#pragma unroll
  for (int q = 0; q < 8; ++q) {
    int f = q * 256 + l * 4;
    float4 v = *(const float4*)(src + f);
    int row = f >> 7, col = f & 127;
    ushort4 h;
    h.x = bfr(v.x); h.y = bfr(v.y); h.z = bfr(v.z); h.w = bfr(v.w);
    *(ushort4*)(Xs + row * 136 + col) = h;
  }
  LGKM_GUARD();

  bf16x8 af[4];
#pragma unroll
  for (int kt = 0; kt < 4; ++kt)
    af[kt] = *(const bf16x8*)(Xs + lr * 136 + kt * 32 + lg * 8);
  LGKM_GUARD();                                   // WAR: af done before Qs overwrite

  const f32x4 zr = {0.f, 0.f, 0.f, 0.f};
  f32x4 qa[8];
#pragma unroll
  for (int ct = 0; ct < 8; ++ct) qa[ct] = zr;
#pragma unroll
  for (int kt = 0; kt < 4; ++kt)
#pragma unroll
    for (int ct = 0; ct < 8; ++ct) {
      bf16x8 bfrg = *(const bf16x8*)(Wq2 + (kt * 128 + ct * 16 + lr) * 32 + lg * 8);
      qa[ct] = MFMA16(af[kt], bfrg, qa[ct]);
    }
#pragma unroll
  for (int ct = 0; ct < 8; ++ct)
#pragma unroll
    for (int r = 0; r < 4; ++r)
      Xs[(lg * 4 + r) * 136 + ct * 16 + lr] = bfr((qa[ct][r] + bq[ct * 16 + lr]) * QSCL);
  LGKM_GUARD();                                   // cross-lane RAW before frag reads

  unsigned short* qdst = Qf + ((size_t)(b * 1024 + nt) * 4) * 512 + lr * 32 + lg * 8;
#pragma unroll
  for (int t = 0; t < 4; ++t) {
    bf16x8 qv = *(const bf16x8*)(Xs + lr * 136 + t * 32 + lg * 8);
    *(bf16x8*)(qdst + t * 512) = qv;
  }
}

// ======== K4: attention + out-proj; Q/K/V frag-major from global; 33 KB LDS ==============
// grid (256, 8): per wave one 16-row n-tile. 4 blocks/CU target.
__global__ __launch_bounds__(256, 4) void attn_kernel(
    const unsigned short* __restrict__ Qf, const float* __restrict__ bp,
    const unsigned short* __restrict__ Wp2,
    const unsigned short* __restrict__ K2, const unsigned short* __restrict__ V2,
    float* __restrict__ out) {
  const int tid = threadIdx.x;
  const int wave = tid >> 6, l = tid & 63, lg = l >> 4, lr = l & 15;
  const int b = blockIdx.y;
  const int nt = blockIdx.x * 4 + wave;

  __shared__ __align__(16) unsigned short PS[4][16 * 264];
  unsigned short* Ps = &PS[wave][0];

  const f32x4 zr = {0.f, 0.f, 0.f, 0.f};
  f32x4 oacc[2][4];
#pragma unroll
  for (int h2 = 0; h2 < 2; ++h2)
#pragma unroll
    for (int dt = 0; dt < 4; ++dt) oacc[h2][dt] = zr;

  const unsigned short* qbase = Qf + ((size_t)(b * 1024 + nt) * 4) * 512 + lr * 32 + lg * 8;

  for (int h = 0; h < 2; ++h) {
    f32x4 sacc[16];
#pragma unroll
    for (int mt = 0; mt < 16; ++mt) sacc[mt] = zr;
#pragma unroll
    for (int d0i = 0; d0i < 2; ++d0i) {
      bf16x8 qfv = *(const bf16x8*)(qbase + (h * 2 + d0i) * 512);
      const unsigned short* kbase = K2 + (size_t)((b * 2 + h) * 2 + d0i) * 8192;
#pragma unroll
      for (int mt = 0; mt < 16; ++mt) {
        bf16x8 kf = *(const bf16x8*)(kbase + (mt * 16 + lr) * 32 + lg * 8);
        sacc[mt] = MFMA16(kf, qfv, sacc[mt]);
      }
    }
    // softmax over m=256 (base-2: Q pre-scaled by log2e)
    float mx = -1e30f;
#pragma unroll
    for (int mt = 0; mt < 16; ++mt)
#pragma unroll
      for (int r = 0; r < 4; ++r) mx = fmaxf(mx, sacc[mt][r]);
    mx = fmaxf(mx, __shfl_xor(mx, 16));
    mx = fmaxf(mx, __shfl_xor(mx, 32));
    float sum = 0.f;
#pragma unroll
    for (int mt = 0; mt < 16; ++mt)
#pragma unroll
      for (int r = 0; r < 4; ++r) {
        float pv = exp2f(sacc[mt][r] - mx);
        sacc[mt][r] = pv; sum += pv;
      }
    sum += __shfl_xor(sum, 16);
    sum += __shfl_xor(sum, 32);
    float inv = 1.f / sum;
    if (h == 1) LGKM_GUARD();                     // WAR: h0 pf reads done before P overwrite
#pragma unroll
    for (int mt = 0; mt < 16; ++mt) {
      uint2 pw;
      pw.x = pk2(sacc[mt][0] * inv, sacc[mt][1] * inv);
      pw.y = pk2(sacc[mt][2] * inv, sacc[mt][3] * inv);
      *(uint2*)(Ps + lr * 264 + mt * 16 + lg * 4) = pw;   // P[n=lr][m]
    }

    // PV: O[16 n][64 d] += P @ V_h
#pragma unroll
    for (int ki = 0; ki < 8; ++ki) {
      const unsigned short* vbase = V2 + (size_t)((b * 2 + h) * 8 + ki) * 2048;
      bf16x8 pf = *(const bf16x8*)(Ps + lr * 264 + ki * 32 + lg * 8);
#pragma unroll
      for (int dt = 0; dt < 4; ++dt) {
        bf16x8 vf = *(const bf16x8*)(vbase + (dt * 16 + lr) * 32 + lg * 8);
        oacc[h][dt] = MFMA16(pf, vf, oacc[h][dt]);
      }
    }
  }  // head

  LGKM_GUARD();                                   // WAR: pf reads done before O overwrite
#pragma unroll
  for (int h = 0; h < 2; ++h)
#pragma unroll
    for (int dt = 0; dt < 4; ++dt)
#pragma unroll
      for (int r = 0; r < 4; ++r)
        Ps[(lg * 4 + r) * 136 + h * 64 + dt * 16 + lr] = bfr(oacc[h][dt][r]);
  LGKM_GUARD();                                   // cross-lane RAW before frag reads

  bf16x8 af2[4];
#pragma unroll
  for (int kt = 0; kt < 4; ++kt)
    af2[kt] = *(const bf16x8*)(Ps + lr * 136 + kt * 32 + lg * 8);
  LGKM_GUARD();                                   // WAR: af2 done before Osf overwrite

  f32x4 yacc[8];
#pragma unroll
  for (int ct = 0; ct < 8; ++ct) yacc[ct] = zr;
#pragma unroll
  for (int kt = 0; kt < 4; ++kt)
#pragma unroll
    for (int ct = 0; ct < 8; ++ct) {
      bf16x8 bfrg = *(const bf16x8*)(Wp2 + (kt * 128 + ct * 16 + lr) * 32 + lg * 8);
      yacc[ct] = MFMA16(af2[kt], bfrg, yacc[ct]);
    }

  float* Osf = (float*)Ps;                        // [16][132] f32
#pragma unroll
  for (int ct = 0; ct < 8; ++ct)
#pragma unroll
    for (int r = 0; r < 4; ++r)
      Osf[(lg * 4 + r) * 132 + ct * 16 + lr] = yacc[ct][r] + bp[ct * 16 + lr];
  LGKM_GUARD();                                   // cross-lane RAW before coalesced read

  {
    float* dst = out + ((size_t)b * 16384 + nt * 16) * 128;
#pragma unroll
    for (int q = 0; q < 8; ++q) {
      int f = q * 256 + l * 4;
      int row = f >> 7, col = f & 127;
      float4 v = *(const float4*)(Osf + row * 132 + col);
      *(float4*)(dst + f) = v;
    }
  }
}

extern "C" void kernel_launch(void* const* d_in, const int* in_sizes, int n_in,
                              void* d_out, int out_size, void* d_ws, size_t ws_size,
                              hipStream_t stream) {
  const float* x = (const float*)d_in[0];
  const float* Wq = (const float*)d_in[3];
  const float* bq = (const float*)d_in[4];
  const float* Wkv = (const float*)d_in[5];
  const float* bkv = (const float*)d_in[6];
  const float* Wp = (const float*)d_in[7];
  const float* bp = (const float*)d_in[8];
  const float* Wsr = (const float*)d_in[9];
  const float* bsr = (const float*)d_in[10];
  const float* gamma = (const float*)d_in[11];
  const float* beta = (const float*)d_in[12];
  float* out = (float*)d_out;

  unsigned short* ws = (unsigned short*)d_ws;
  unsigned short* Wq2 = ws;                   // 16384
  unsigned short* Wp2 = ws + 16384;           // 16384
  unsigned short* Wkv2 = ws + 32768;          // 32768
  unsigned short* W2sr = ws + 65536;          // 1048576
  unsigned short* K2 = ws + 1114112;          // 262144
  unsigned short* V2 = ws + 1376256;          // 262144
  unsigned short* Qf = ws + 1638400;          // 16777216  [b][ntile][4][512]
  float* scratch = (float*)(ws + 18415616);   // 16*2048*128 f32 = 16.8 MB

  prep_kernel<<<320, 256, 0, stream>>>(Wq, Wkv, Wp, Wsr, Wq2, Wkv2, Wp2, W2sr);
  conv_split_kernel<<<dim3(128, 4), 256, 0, stream>>>(x, W2sr, scratch);
  ln_kv_kernel<<<128, 256, 0, stream>>>(scratch, bsr, gamma, beta, Wkv2, bkv, K2, V2);
  qproj_kernel<<<dim3(256, 8), 256, 0, stream>>>(x, bq, Wq2, Qf);
  attn_kernel<<<dim3(256, 8), 256, 0, stream>>>(Qf, bp, Wp2, K2, V2, out);
}